// Round 12
// baseline (1739.591 us; speedup 1.0000x reference)
//
#include <hip/hip_runtime.h>
#include <hip/hip_bf16.h>

typedef __bf16 bf16_t;
typedef __bf16 bf16x8 __attribute__((ext_vector_type(8)));
typedef float  f32x4  __attribute__((ext_vector_type(4)));

#define DEV static __device__ __forceinline__

DEV void gload16(const bf16_t* g, bf16_t* l) {
    __builtin_amdgcn_global_load_lds(
        (const __attribute__((address_space(1))) void*)g,
        (__attribute__((address_space(3))) void*)l, 16, 0, 0);
}

enum { EPI_F32 = 0, EPI_BF16 = 1, EPI_RES = 2, EPI_GELU = 3, EPI_MUL = 4 };

#define G_MFMA(d, a, b) d = __builtin_amdgcn_mfma_f32_16x16x32_bf16(a, b, d, 0, 0, 0)

// ---------------------------------------------------------------------------
// gemma: 256x256-tile, BK=64, 8 waves (2Mx4N) pipelined GEMM (r11 structure,
// best measured).  Zero-conflict LDS swizzle; precomputed bases; split-K via
// blockIdx.z.  Requires M,N % 256 == 0, Kd % 128 == 0.
// ---------------------------------------------------------------------------
#define COMPUTE(AB0, AB1, BB0, BB1)                                           \
  { bf16x8 aF[8], bF[4];                                                      \
    _Pragma("unroll") for (int m8 = 0; m8 < 8; m8++)                          \
      aF[m8] = *(const bf16x8*)(AB0 + (m8 >> 2) * 4096 + (m8 & 3) * 1024);    \
    _Pragma("unroll") for (int nj = 0; nj < 4; nj++)                          \
      bF[nj] = *(const bf16x8*)(BB0 + nj * 1024);                             \
    _Pragma("unroll") for (int m8 = 0; m8 < 8; m8++)                          \
      _Pragma("unroll") for (int nj = 0; nj < 4; nj++)                        \
        G_MFMA(acc[m8][nj], aF[m8], bF[nj]);                                  \
    _Pragma("unroll") for (int m8 = 0; m8 < 8; m8++)                          \
      aF[m8] = *(const bf16x8*)(AB1 + (m8 >> 2) * 4096 + (m8 & 3) * 1024);    \
    _Pragma("unroll") for (int nj = 0; nj < 4; nj++)                          \
      bF[nj] = *(const bf16x8*)(BB1 + nj * 1024);                             \
    _Pragma("unroll") for (int m8 = 0; m8 < 8; m8++)                          \
      _Pragma("unroll") for (int nj = 0; nj < 4; nj++)                        \
        G_MFMA(acc[m8][nj], aF[m8], bF[nj]);                                  \
  }

#define STAGE8(kt, bi)                                                        \
  { SCA(kt, bi, 0); SCA(kt, bi, 1); SCA(kt, bi, 2); SCA(kt, bi, 3);           \
    SCB(kt, bi, 0); SCB(kt, bi, 1); SCB(kt, bi, 2); SCB(kt, bi, 3); }

template<int EPI>
__global__ __launch_bounds__(512, 1)
void gemma(const bf16_t* __restrict__ A, const bf16_t* __restrict__ Bt,
           void* __restrict__ Cout, int Kd, int lda, int ldb, int ldc,
           long sCz,
           const float* __restrict__ res, const float* __restrict__ gate,
           int gateStride, int rowsPerB, const bf16_t* __restrict__ aux)
{
    const int nbx = gridDim.x;
    const int nwg = nbx * gridDim.y;
    int lin = blockIdx.y * nbx + blockIdx.x;
    const int q8 = nwg >> 3, r8 = nwg & 7;
    const int xcd = lin & 7, oo = lin >> 3;
    lin = (xcd < r8 ? xcd * (q8 + 1) : r8 * (q8 + 1) + (xcd - r8) * q8) + oo;
    const long m0 = (long)(lin / nbx) * 256;
    const long n0 = (long)(lin % nbx) * 256;
    const long kb = (long)blockIdx.z * Kd;

    const int tid = threadIdx.x;
    const int l   = tid & 63;
    const int w   = tid >> 6;
    const int wr  = w >> 2;
    const int wcn = w & 3;

    __shared__ bf16_t sA[2][16384];
    __shared__ bf16_t sB[2][16384];

    const long sgc = (long)(((l & 7) ^ (l >> 3)) << 3);
    const int NT = Kd >> 6;
    const int NI = NT >> 1;

    const bf16_t* pA0 = A + (m0 + 0 * 64 + w * 8 + (l >> 3)) * (long)lda + kb + sgc;
    const bf16_t* pA1 = A + (m0 + 1 * 64 + w * 8 + (l >> 3)) * (long)lda + kb + sgc;
    const bf16_t* pA2 = A + (m0 + 2 * 64 + w * 8 + (l >> 3)) * (long)lda + kb + sgc;
    const bf16_t* pA3 = A + (m0 + 3 * 64 + w * 8 + (l >> 3)) * (long)lda + kb + sgc;
    const bf16_t* pB0 = Bt + (n0 + 0 * 64 + w * 8 + (l >> 3)) * (long)ldb + kb + sgc;
    const bf16_t* pB1 = Bt + (n0 + 1 * 64 + w * 8 + (l >> 3)) * (long)ldb + kb + sgc;
    const bf16_t* pB2 = Bt + (n0 + 2 * 64 + w * 8 + (l >> 3)) * (long)ldb + kb + sgc;
    const bf16_t* pB3 = Bt + (n0 + 3 * 64 + w * 8 + (l >> 3)) * (long)ldb + kb + sgc;

#define SCA(kt, bi, c) gload16(pA##c + (kt), &sA[bi][(c) * 4096 + w * 512])
#define SCB(kt, bi, c) gload16(pB##c + (kt), &sB[bi][(c) * 4096 + w * 512])

    f32x4 acc[8][4];
#pragma unroll
    for (int i = 0; i < 8; i++)
#pragma unroll
        for (int j = 0; j < 4; j++) acc[i][j] = f32x4{0.f, 0.f, 0.f, 0.f};

    const int co0 = ((l >> 4) ^ (l & 7)) << 3;
    const int co1 = ((4 + (l >> 4)) ^ (l & 7)) << 3;

    const bf16_t* rbA00 = &sA[0][(wr * 128 + (l & 15)) * 64 + co0];
    const bf16_t* rbA01 = &sA[0][(wr * 128 + (l & 15)) * 64 + co1];
    const bf16_t* rbA10 = &sA[1][(wr * 128 + (l & 15)) * 64 + co0];
    const bf16_t* rbA11 = &sA[1][(wr * 128 + (l & 15)) * 64 + co1];
    const bf16_t* rbB00 = &sB[0][(wcn * 64 + (l & 15)) * 64 + co0];
    const bf16_t* rbB01 = &sB[0][(wcn * 64 + (l & 15)) * 64 + co1];
    const bf16_t* rbB10 = &sB[1][(wcn * 64 + (l & 15)) * 64 + co0];
    const bf16_t* rbB11 = &sB[1][(wcn * 64 + (l & 15)) * 64 + co1];

    STAGE8(0, 0);

    for (int it = 0; it < NI; ++it) {
        const int v = 2 * it + 1;
        asm volatile("s_waitcnt lgkmcnt(0)" ::: "memory");
        __builtin_amdgcn_s_barrier();
        STAGE8((long)v * 64, 1);
        asm volatile("s_waitcnt vmcnt(8)" ::: "memory");
        __builtin_amdgcn_s_barrier();
        COMPUTE(rbA00, rbA01, rbB00, rbB01);
        asm volatile("s_waitcnt lgkmcnt(0)" ::: "memory");
        __builtin_amdgcn_s_barrier();
        if (v + 1 < NT) {
            STAGE8((long)(v + 1) * 64, 0);
            asm volatile("s_waitcnt vmcnt(8)" ::: "memory");
        } else {
            asm volatile("s_waitcnt vmcnt(0)" ::: "memory");
        }
        __builtin_amdgcn_s_barrier();
        COMPUTE(rbA10, rbA11, rbB10, rbB11);
    }

#pragma unroll
    for (int mi = 0; mi < 8; mi++) {
#pragma unroll
        for (int nj = 0; nj < 4; nj++) {
            f32x4 vv = acc[mi][nj];
            const long col   = n0 + wcn * 64 + nj * 16 + (l & 15);
            const long row0r = m0 + wr * 128 + mi * 16 + ((l >> 4) * 4);
#pragma unroll
            for (int e = 0; e < 4; e++) {
                const long row = row0r + e;
                const long idx = row * (long)ldc + col + (long)blockIdx.z * sCz;
                const float val = vv[e];
                if constexpr (EPI == EPI_F32) {
                    ((float*)Cout)[idx] = val;
                } else if constexpr (EPI == EPI_BF16) {
                    ((bf16_t*)Cout)[idx] = (bf16_t)val;
                } else if constexpr (EPI == EPI_RES) {
                    const int b = (int)(row / rowsPerB);
                    ((float*)Cout)[idx] = res[row * (long)ldc + col] + val * gate[(long)b * gateStride + col];
                } else if constexpr (EPI == EPI_GELU) {
                    const float gl = 0.5f * val * (1.f + tanhf(0.7978845608f * (val + 0.044715f * val * val * val)));
                    ((bf16_t*)Cout)[idx] = (bf16_t)gl;
                } else if constexpr (EPI == EPI_MUL) {
                    ((bf16_t*)Cout)[idx] = (bf16_t)((float)aux[idx] * val);
                }
            }
        }
    }
#undef SCA
#undef SCB
}

// out = res + (P[z=0] + P[z=1]) * gate   (split-K combine, fp32, float4)
__global__ __launch_bounds__(256)
void combine_splitk(const float* __restrict__ P, const float* __restrict__ res,
                    const float* __restrict__ gate, float* __restrict__ out,
                    int D, int T, int gateStride, long zstride, long n4)
{
    for (long i4 = (long)blockIdx.x * 256 + threadIdx.x; i4 < n4; i4 += (long)gridDim.x * 256) {
        const long i = i4 * 4;
        const float4 p0 = *(const float4*)(P + i);
        const float4 p1 = *(const float4*)(P + i + zstride);
        const float4 xv = *(const float4*)(res + i);
        const long row = i / D;
        const int  b   = (int)(row / T);
        const int  col = (int)(i - row * D);
        const float* gp = gate + (long)b * gateStride + col;
        float4 r;
        r.x = xv.x + (p0.x + p1.x) * gp[0];
        r.y = xv.y + (p0.y + p1.y) * gp[1];
        r.z = xv.z + (p0.z + p1.z) * gp[2];
        r.w = xv.w + (p0.w + p1.w) * gp[3];
        *(float4*)(out + i) = r;
    }
}

// ---------------------------------------------------------------------------
// flash_attn: causal GQA flash attention.  One block = 64 q-rows of one
// (b,g); 4 waves x 16 rows (each wave owns FULL rows -> softmax reduce is a
// width-16 shfl_xor, no cross-wave sync at all).  Q/K/V read from global
// (Kr/VT are 1-2MB, L2-resident; Q-frags hoisted to regs).  P staged bf16 in
// per-wave-private LDS rows (DS ops are in-order per wave -> no barrier).
// Fragment layouts identical to the verified gemm_bt usage:
//   A: row=l&15, k=(l>>4)*8+e;  B: col=l&15, same k;  C/D: col=l&15,
//   row=(l>>4)*4+e.
// Qr: [B*G, T, H] (pre-scaled by H^-0.5); Kr: [B, S, H]; VT: [B, H, S];
// ENC: [B*T, G*H].
// ---------------------------------------------------------------------------
__global__ __launch_bounds__(256)
void flash_attn(const bf16_t* __restrict__ Qr, const bf16_t* __restrict__ Kr,
                const bf16_t* __restrict__ VT, bf16_t* __restrict__ ENC,
                int T, int H, int S)
{
    const int qt = blockIdx.x;          // q-tile (64 rows)
    const int bg = blockIdx.y;          // b*8 + g
    const int b  = bg >> 3;
    const int g  = bg & 7;
    const int tid = threadIdx.x;
    const int l  = tid & 63;
    const int w  = tid >> 6;            // wave: q rows [qt*64 + w*16, +16)
    const int lr = l & 15;
    const int lg = l >> 4;

    __shared__ bf16_t P[64][136];       // pad 8: 16B-aligned rows, bank-spread

    // Q fragments (16 rows x K=256) hoisted to registers
    const long qbase = ((long)bg * T + qt * 64 + w * 16 + lr) * H;
    bf16x8 qf[8];
#pragma unroll
    for (int ks = 0; ks < 8; ks++)
        qf[ks] = *(const bf16x8*)(Qr + qbase + ks * 32 + lg * 8);

    const bf16_t* Kb = Kr + (long)b * T * H;
    const bf16_t* Vb = VT + (long)b * H * S;

    f32x4 o[16];
#pragma unroll
    for (int j = 0; j < 16; j++) o[j] = f32x4{0.f, 0.f, 0.f, 0.f};
    float m[4]    = {-3.0e38f, -3.0e38f, -3.0e38f, -3.0e38f};
    float lsum[4] = {0.f, 0.f, 0.f, 0.f};

    const int q_lo = qt * 64 + w * 16;  // wave's first global q row
    const int nt = (qt >> 1) + 1;       // causal: s tiles 0..nt-1 cover s<=q_hi

    for (int kt = 0; kt < nt; kt++) {
        // ---- S = Q K^T (16 x 128) ----
        f32x4 s[8];
#pragma unroll
        for (int j = 0; j < 8; j++) s[j] = f32x4{0.f, 0.f, 0.f, 0.f};
#pragma unroll
        for (int ks = 0; ks < 8; ks++) {
#pragma unroll
            for (int j = 0; j < 8; j++) {
                const bf16x8 kf = *(const bf16x8*)(Kb + (long)(kt * 128 + j * 16 + lr) * H + ks * 32 + lg * 8);
                G_MFMA(s[j], qf[ks], kf);
            }
        }
        // ---- causal mask + row max ----
        float smax[4] = {-3.0e38f, -3.0e38f, -3.0e38f, -3.0e38f};
#pragma unroll
        for (int j = 0; j < 8; j++) {
            const int sg = kt * 128 + j * 16 + lr;
#pragma unroll
            for (int e = 0; e < 4; e++) {
                const int qg = q_lo + lg * 4 + e;
                if (sg > qg) s[j][e] = -3.0e38f;
                smax[e] = fmaxf(smax[e], s[j][e]);
            }
        }
#pragma unroll
        for (int off = 1; off < 16; off <<= 1)
#pragma unroll
            for (int e = 0; e < 4; e++)
                smax[e] = fmaxf(smax[e], __shfl_xor(smax[e], off, 16));
        // ---- online update ----
        float scale[4];
#pragma unroll
        for (int e = 0; e < 4; e++) {
            const float mn = fmaxf(m[e], smax[e]);
            scale[e] = __expf(m[e] - mn);
            m[e] = mn;
        }
        // ---- P = exp(S - m), row sums, write LDS ----
        float rs[4] = {0.f, 0.f, 0.f, 0.f};
#pragma unroll
        for (int j = 0; j < 8; j++)
#pragma unroll
            for (int e = 0; e < 4; e++) {
                const float p = __expf(s[j][e] - m[e]);
                rs[e] += p;
                P[w * 16 + lg * 4 + e][j * 16 + lr] = (bf16_t)p;
            }
#pragma unroll
        for (int off = 1; off < 16; off <<= 1)
#pragma unroll
            for (int e = 0; e < 4; e++)
                rs[e] += __shfl_xor(rs[e], off, 16);
#pragma unroll
        for (int e = 0; e < 4; e++) lsum[e] = lsum[e] * scale[e] + rs[e];
        // ---- rescale O ----
#pragma unroll
        for (int j = 0; j < 16; j++)
#pragma unroll
            for (int e = 0; e < 4; e++) o[j][e] *= scale[e];
        // ---- O += P @ V (A from LDS, B from global VT) ----
#pragma unroll
        for (int ks = 0; ks < 4; ks++) {
            const bf16x8 pa = *(const bf16x8*)(&P[w * 16 + lr][ks * 32 + lg * 8]);
#pragma unroll
            for (int j = 0; j < 16; j++) {
                const bf16x8 vf = *(const bf16x8*)(Vb + (long)(j * 16 + lr) * S + kt * 128 + ks * 32 + lg * 8);
                G_MFMA(o[j], pa, vf);
            }
        }
    }

    // ---- epilogue: O / lsum -> ENC[b*T + t][g*H + h] ----
    float inv[4];
#pragma unroll
    for (int e = 0; e < 4; e++) inv[e] = 1.f / lsum[e];
#pragma unroll
    for (int j = 0; j < 16; j++)
#pragma unroll
        for (int e = 0; e < 4; e++) {
            const int t = qt * 64 + w * 16 + lg * 4 + e;
            ENC[((long)b * T + t) * 2048 + g * 256 + j * 16 + lr] = (bf16_t)(o[j][e] * inv[e]);
        }
}

// fp32 [R,C] -> bf16 [C,R] transpose (batched via blockIdx.z)
__global__ __launch_bounds__(256)
void transpose_f2b(const float* __restrict__ in, bf16_t* __restrict__ out,
                   int R, int C, long inStride, long outStride)
{
    __shared__ float tile[32][33];
    in  += (long)blockIdx.z * inStride;
    out += (long)blockIdx.z * outStride;
    const int c0 = blockIdx.x * 32, r0 = blockIdx.y * 32;
    const int tx = threadIdx.x, ty = threadIdx.y;
#pragma unroll
    for (int i = 0; i < 4; i++)
        tile[ty + i * 8][tx] = in[(long)(r0 + ty + i * 8) * C + c0 + tx];
    __syncthreads();
#pragma unroll
    for (int i = 0; i < 4; i++)
        out[(long)(c0 + ty + i * 8) * R + r0 + tx] = (bf16_t)tile[tx][ty + i * 8];
}

// mod = cond @ Wmod + bmod, two-stage K-split (deterministic)
__global__ __launch_bounds__(256)
void modk_part(const float* __restrict__ cond, const float* __restrict__ W,
               float* __restrict__ part, int D3, int KS)
{
    const int j = blockIdx.x * 256 + threadIdx.x;
    const int b = blockIdx.y;
    const int z = blockIdx.z;
    const float* cb = cond + (long)b * (KS * gridDim.z);
    float s = 0.f;
    const int d0 = z * KS;
#pragma unroll 4
    for (int d = d0; d < d0 + KS; d++) s += cb[d] * W[(long)d * D3 + j];
    part[((long)z * gridDim.y + b) * D3 + j] = s;
}

__global__ __launch_bounds__(256)
void modk_reduce(const float* __restrict__ part, const float* __restrict__ bvec,
                 float* __restrict__ mod, int D3, int NZ)
{
    const int j = blockIdx.x * 256 + threadIdx.x;
    const int b = blockIdx.y;
    float s = bvec[j];
    for (int z = 0; z < NZ; z++) s += part[((long)z * gridDim.y + b) * D3 + j];
    mod[(long)b * D3 + j] = s;
}

// RMSNorm (fp32) + AdaLN scale/shift -> bf16.  One block per row, D=2048.
__global__ __launch_bounds__(256)
void rmsnorm_adaln(const float* __restrict__ xin, const float* __restrict__ mod,
                   bf16_t* __restrict__ out, int D, int T, int D3)
{
    const long row = blockIdx.x;
    const int  b   = (int)(row / T);
    const int  tid = threadIdx.x;
    const float4* x4 = (const float4*)(xin + row * (long)D);
    const float4 v0 = x4[tid], v1 = x4[tid + 256];
    float ss = v0.x * v0.x + v0.y * v0.y + v0.z * v0.z + v0.w * v0.w
             + v1.x * v1.x + v1.y * v1.y + v1.z * v1.z + v1.w * v1.w;
    for (int o = 32; o; o >>= 1) ss += __shfl_down(ss, o, 64);
    __shared__ float red[4];
    if ((tid & 63) == 0) red[tid >> 6] = ss;
    __syncthreads();
    ss = red[0] + red[1] + red[2] + red[3];
    const float rs = rsqrtf(ss / (float)D + 1e-6f);
    const float* sc = mod + (long)b * D3;
    const float* sh = sc + D;
    const float4 s0 = ((const float4*)sc)[tid], s1 = ((const float4*)sc)[tid + 256];
    const float4 h0 = ((const float4*)sh)[tid], h1 = ((const float4*)sh)[tid + 256];
    bf16_t* orow = out + row * (long)D;
    orow[tid * 4 + 0]         = (bf16_t)(v0.x * rs * (1.f + s0.x) + h0.x);
    orow[tid * 4 + 1]         = (bf16_t)(v0.y * rs * (1.f + s0.y) + h0.y);
    orow[tid * 4 + 2]         = (bf16_t)(v0.z * rs * (1.f + s0.z) + h0.z);
    orow[tid * 4 + 3]         = (bf16_t)(v0.w * rs * (1.f + s0.w) + h0.w);
    orow[(tid + 256) * 4 + 0] = (bf16_t)(v1.x * rs * (1.f + s1.x) + h1.x);
    orow[(tid + 256) * 4 + 1] = (bf16_t)(v1.y * rs * (1.f + s1.y) + h1.y);
    orow[(tid + 256) * 4 + 2] = (bf16_t)(v1.z * rs * (1.f + s1.z) + h1.z);
    orow[(tid + 256) * 4 + 3] = (bf16_t)(v1.w * rs * (1.f + s1.w) + h1.w);
}

// RoPE on q (+ H^-0.5 scale), [BT,ldq] bf16 -> [B,N,T,H] bf16
__global__ __launch_bounds__(128)
void rope_q(const bf16_t* __restrict__ qp, const float* __restrict__ positions,
            bf16_t* __restrict__ qo, int T, int ldq, int H)
{
    const int t = blockIdx.x, n = blockIdx.y, b = blockIdx.z;
    const int i = threadIdx.x;
    const long in0 = ((long)(b * T + t)) * ldq + n * H;
    const float x1 = (float)qp[in0 + i];
    const float x2 = (float)qp[in0 + i + 128];
    const float pos = positions[b * T + t];
    const float inv = expf(-9.210340371976184f * (float)i / 128.f);
    float s, c;
    sincosf(pos * inv, &s, &c);
    const float scl = 0.0625f;
    const long out0 = (((long)(b * 8 + n)) * T + t) * H;
    qo[out0 + i]       = (bf16_t)((x1 * c - x2 * s) * scl);
    qo[out0 + i + 128] = (bf16_t)((x2 * c + x1 * s) * scl);
}

// RoPE on k + transpose v.  kvp: [BT][ldkv] bf16 (cols 0..255 k, 256..511 v)
__global__ __launch_bounds__(128)
void rope_kv(const bf16_t* __restrict__ kvp, const float* __restrict__ positions,
             bf16_t* __restrict__ ko, bf16_t* __restrict__ vt, int T, int H, int S, int ldkv)
{
    const int t = blockIdx.x, b = blockIdx.y;
    const int i = threadIdx.x;
    const long in0 = ((long)(b * T + t)) * ldkv;
    const float k1 = (float)kvp[in0 + i];
    const float k2 = (float)kvp[in0 + i + 128];
    const float pos = positions[b * T + t];
    const float inv = expf(-9.210340371976184f * (float)i / 128.f);
    float s, c;
    sincosf(pos * inv, &s, &c);
    const long ko0 = ((long)(b * T + t)) * H;
    ko[ko0 + i]       = (bf16_t)(k1 * c - k2 * s);
    ko[ko0 + i + 128] = (bf16_t)(k2 * c + k1 * s);
    vt[((long)b * H + i) * S + t]       = kvp[in0 + 256 + i];
    vt[((long)b * H + i + 128) * S + t] = kvp[in0 + 256 + i + 128];
}

extern "C" void kernel_launch(void* const* d_in, const int* in_sizes, int n_in,
                              void* d_out, int out_size, void* d_ws, size_t ws_size,
                              hipStream_t stream)
{
    const float* x      = (const float*)d_in[0];
    const float* pos    = (const float*)d_in[1];
    const float* cond   = (const float*)d_in[3];
    const float* Wmod_a = (const float*)d_in[4];
    const float* bmod_a = (const float*)d_in[5];
    const float* Wq     = (const float*)d_in[6];
    const float* Wkv    = (const float*)d_in[7];
    const float* Wo     = (const float*)d_in[8];
    const float* Wmod_f = (const float*)d_in[9];
    const float* bmod_f = (const float*)d_in[10];
    const float* Wg     = (const float*)d_in[11];
    const float* Wl     = (const float*)d_in[12];

    constexpr int  Bb = 2, T = 2048, D = 2048, F = 16384, Nh = 8, H = 256;
    constexpr int  NH = 2048, S = 2048, BT = 4096, D3 = 6144;
    constexpr int  KSLICE = 64, NZ = D / KSLICE;
    constexpr int  NQKV = 2560;   // fused Q(2048) + K(256) + V(256)

    char* ws = (char*)d_ws;
    size_t off = 0;
    auto alloc = [&](size_t bytes) { char* p = ws + off; off += bytes; return p; };

    bf16_t* WQT  = (bf16_t*)alloc((size_t)NH * D * 2);      // rows 0-2047
    bf16_t* WKVT = (bf16_t*)alloc((size_t)512 * D * 2);     // rows 2048-2559 (contiguous)
    bf16_t* WOT  = (bf16_t*)alloc((size_t)D * NH * 2);
    bf16_t* WGT  = (bf16_t*)alloc((size_t)2 * F * D * 2);
    bf16_t* WLT  = (bf16_t*)alloc((size_t)D * F * 2);
    float*  MODA = (float*)alloc((size_t)Bb * D3 * 4);
    float*  MODF = (float*)alloc((size_t)Bb * D3 * 4);
    float*  PART = (float*)alloc((size_t)NZ * Bb * D3 * 4);
    bf16_t* NA   = (bf16_t*)alloc((size_t)BT * D * 2);
    bf16_t* QKVP = (bf16_t*)alloc((size_t)BT * NQKV * 2);
    bf16_t* Qr   = (bf16_t*)alloc((size_t)Bb * Nh * T * H * 2);
    bf16_t* Kr   = (bf16_t*)alloc((size_t)Bb * T * H * 2);
    bf16_t* VT   = (bf16_t*)alloc((size_t)Bb * H * S * 2);
    bf16_t* ENC  = (bf16_t*)alloc((size_t)BT * NH * 2);
    float*  X1   = (float*)alloc((size_t)BT * D * 4);
    bf16_t* NF   = (bf16_t*)alloc((size_t)BT * D * 2);
    const size_t hBytes = (size_t)BT * F * 2;               // 128 MB
    char* big = alloc(hBytes + (size_t)2 * BT * D * 4);     // Hb + split-K partials
    bf16_t* Hb    = (bf16_t*)big;
    float*  PARTK = (float*)(big + hBytes);                 // 64 MB (2 z-planes)
    (void)ws_size; (void)in_sizes; (void)n_in; (void)out_size;

    const dim3 tb(32, 8);
    transpose_f2b<<<dim3(H / 32, D / 32, 8), tb, 0, stream>>>(Wq,  WQT,  D,  H, (long)D * H, (long)H * D);
    transpose_f2b<<<dim3(H / 32, D / 32, 2), tb, 0, stream>>>(Wkv, WKVT, D,  H, (long)D * H, (long)H * D);
    transpose_f2b<<<dim3(D / 32, NH / 32, 1), tb, 0, stream>>>(Wo, WOT, NH,  D, 0, 0);
    transpose_f2b<<<dim3(F / 32, D / 32, 2), tb, 0, stream>>>(Wg,  WGT,  D,  F, (long)D * F, (long)F * D);
    transpose_f2b<<<dim3(D / 32, F / 32, 1), tb, 0, stream>>>(Wl,  WLT,  F,  D, 0, 0);
    modk_part<<<dim3(D3 / 256, Bb, NZ), 256, 0, stream>>>(cond, Wmod_a, PART, D3, KSLICE);
    modk_reduce<<<dim3(D3 / 256, Bb), 256, 0, stream>>>(PART, bmod_a, MODA, D3, NZ);
    modk_part<<<dim3(D3 / 256, Bb, NZ), 256, 0, stream>>>(cond, Wmod_f, PART, D3, KSLICE);
    modk_reduce<<<dim3(D3 / 256, Bb), 256, 0, stream>>>(PART, bmod_f, MODF, D3, NZ);
    rmsnorm_adaln<<<BT, 256, 0, stream>>>(x, MODA, NA, D, T, D3);
    // fused Q+KV projection
    gemma<EPI_BF16><<<dim3(NQKV / 256, BT / 256, 1), 512, 0, stream>>>(
        NA, WQT, QKVP, D, D, D, NQKV, 0, nullptr, nullptr, 0, 0, nullptr);
    rope_q<<<dim3(T, Nh, Bb), 128, 0, stream>>>(QKVP, pos, Qr, T, NQKV, H);
    rope_kv<<<dim3(T, Bb), 128, 0, stream>>>(QKVP + NH, pos, Kr, VT, T, H, S, NQKV);
    // flash attention (replaces QK / softmax / PV)
    flash_attn<<<dim3(T / 64, Bb * Nh), 256, 0, stream>>>(Qr, Kr, VT, ENC, T, H, S);
    // Wo projection, split-K=2 (full GPU) + combine with gated residual -> X1
    gemma<EPI_F32><<<dim3(D / 256, BT / 256, 2), 512, 0, stream>>>(
        ENC, WOT, PARTK, NH / 2, NH, NH, D, (long)BT * D, nullptr, nullptr, 0, 0, nullptr);
    combine_splitk<<<2048, 256, 0, stream>>>(
        PARTK, x, MODA + 2 * D, X1, D, T, D3, (long)BT * D, (long)BT * D / 4);
    rmsnorm_adaln<<<BT, 256, 0, stream>>>(X1, MODF, NF, D, T, D3);
    // FFN up: h0 = gelu(n@Wg0); h = h0 * (n@Wg1) in-place
    gemma<EPI_GELU><<<dim3(F / 256, BT / 256, 1), 512, 0, stream>>>(
        NF, WGT, Hb, D, D, D, F, 0, nullptr, nullptr, 0, 0, nullptr);
    gemma<EPI_MUL><<<dim3(F / 256, BT / 256, 1), 512, 0, stream>>>(
        NF, WGT + (long)F * D, Hb, D, D, D, F, 0, nullptr, nullptr, 0, 0, Hb);
    // FFN down: split-K=2 partials + fused combine -> out
    gemma<EPI_F32><<<dim3(D / 256, BT / 256, 2), 512, 0, stream>>>(
        Hb, WLT, PARTK, F / 2, F, F, D, (long)BT * D, nullptr, nullptr, 0, 0, nullptr);
    combine_splitk<<<2048, 256, 0, stream>>>(
        PARTK, X1, MODF + 2 * D, (float*)d_out, D, T, D3, (long)BT * D, (long)BT * D / 4);
}

// Round 13
// 1525.862 us; speedup vs baseline: 1.1401x; 1.1401x over previous
//
#include <hip/hip_runtime.h>
#include <hip/hip_bf16.h>

typedef __bf16 bf16_t;
typedef __bf16 bf16x8 __attribute__((ext_vector_type(8)));
typedef float  f32x4  __attribute__((ext_vector_type(4)));

#define DEV static __device__ __forceinline__

DEV void gload16(const bf16_t* g, bf16_t* l) {
    __builtin_amdgcn_global_load_lds(
        (const __attribute__((address_space(1))) void*)g,
        (__attribute__((address_space(3))) void*)l, 16, 0, 0);
}

enum { EPI_F32 = 0, EPI_BF16 = 1, EPI_RES = 2, EPI_GELU = 3, EPI_MUL = 4 };

#define G_MFMA(d, a, b) d = __builtin_amdgcn_mfma_f32_16x16x32_bf16(a, b, d, 0, 0, 0)

// ---------------------------------------------------------------------------
// gemma: 256x256-tile, BK=64, 8 waves (2Mx4N) pipelined GEMM (r11 structure,
// best measured).  Zero-conflict LDS swizzle; precomputed bases; split-K via
// blockIdx.z.  Requires M,N % 256 == 0, Kd % 128 == 0.
// ---------------------------------------------------------------------------
#define COMPUTE(AB0, AB1, BB0, BB1)                                           \
  { bf16x8 aF[8], bF[4];                                                      \
    _Pragma("unroll") for (int m8 = 0; m8 < 8; m8++)                          \
      aF[m8] = *(const bf16x8*)(AB0 + (m8 >> 2) * 4096 + (m8 & 3) * 1024);    \
    _Pragma("unroll") for (int nj = 0; nj < 4; nj++)                          \
      bF[nj] = *(const bf16x8*)(BB0 + nj * 1024);                             \
    _Pragma("unroll") for (int m8 = 0; m8 < 8; m8++)                          \
      _Pragma("unroll") for (int nj = 0; nj < 4; nj++)                        \
        G_MFMA(acc[m8][nj], aF[m8], bF[nj]);                                  \
    _Pragma("unroll") for (int m8 = 0; m8 < 8; m8++)                          \
      aF[m8] = *(const bf16x8*)(AB1 + (m8 >> 2) * 4096 + (m8 & 3) * 1024);    \
    _Pragma("unroll") for (int nj = 0; nj < 4; nj++)                          \
      bF[nj] = *(const bf16x8*)(BB1 + nj * 1024);                             \
    _Pragma("unroll") for (int m8 = 0; m8 < 8; m8++)                          \
      _Pragma("unroll") for (int nj = 0; nj < 4; nj++)                        \
        G_MFMA(acc[m8][nj], aF[m8], bF[nj]);                                  \
  }

#define STAGE8(kt, bi)                                                        \
  { SCA(kt, bi, 0); SCA(kt, bi, 1); SCA(kt, bi, 2); SCA(kt, bi, 3);           \
    SCB(kt, bi, 0); SCB(kt, bi, 1); SCB(kt, bi, 2); SCB(kt, bi, 3); }

template<int EPI>
__global__ __launch_bounds__(512, 1)
void gemma(const bf16_t* __restrict__ A, const bf16_t* __restrict__ Bt,
           void* __restrict__ Cout, int Kd, int lda, int ldb, int ldc,
           long sCz,
           const float* __restrict__ res, const float* __restrict__ gate,
           int gateStride, int rowsPerB, const bf16_t* __restrict__ aux)
{
    const int nbx = gridDim.x;
    const int nwg = nbx * gridDim.y;
    int lin = blockIdx.y * nbx + blockIdx.x;
    const int q8 = nwg >> 3, r8 = nwg & 7;
    const int xcd = lin & 7, oo = lin >> 3;
    lin = (xcd < r8 ? xcd * (q8 + 1) : r8 * (q8 + 1) + (xcd - r8) * q8) + oo;
    const long m0 = (long)(lin / nbx) * 256;
    const long n0 = (long)(lin % nbx) * 256;
    const long kb = (long)blockIdx.z * Kd;

    const int tid = threadIdx.x;
    const int l   = tid & 63;
    const int w   = tid >> 6;
    const int wr  = w >> 2;
    const int wcn = w & 3;

    __shared__ bf16_t sA[2][16384];
    __shared__ bf16_t sB[2][16384];

    const long sgc = (long)(((l & 7) ^ (l >> 3)) << 3);
    const int NT = Kd >> 6;
    const int NI = NT >> 1;

    const bf16_t* pA0 = A + (m0 + 0 * 64 + w * 8 + (l >> 3)) * (long)lda + kb + sgc;
    const bf16_t* pA1 = A + (m0 + 1 * 64 + w * 8 + (l >> 3)) * (long)lda + kb + sgc;
    const bf16_t* pA2 = A + (m0 + 2 * 64 + w * 8 + (l >> 3)) * (long)lda + kb + sgc;
    const bf16_t* pA3 = A + (m0 + 3 * 64 + w * 8 + (l >> 3)) * (long)lda + kb + sgc;
    const bf16_t* pB0 = Bt + (n0 + 0 * 64 + w * 8 + (l >> 3)) * (long)ldb + kb + sgc;
    const bf16_t* pB1 = Bt + (n0 + 1 * 64 + w * 8 + (l >> 3)) * (long)ldb + kb + sgc;
    const bf16_t* pB2 = Bt + (n0 + 2 * 64 + w * 8 + (l >> 3)) * (long)ldb + kb + sgc;
    const bf16_t* pB3 = Bt + (n0 + 3 * 64 + w * 8 + (l >> 3)) * (long)ldb + kb + sgc;

#define SCA(kt, bi, c) gload16(pA##c + (kt), &sA[bi][(c) * 4096 + w * 512])
#define SCB(kt, bi, c) gload16(pB##c + (kt), &sB[bi][(c) * 4096 + w * 512])

    f32x4 acc[8][4];
#pragma unroll
    for (int i = 0; i < 8; i++)
#pragma unroll
        for (int j = 0; j < 4; j++) acc[i][j] = f32x4{0.f, 0.f, 0.f, 0.f};

    const int co0 = ((l >> 4) ^ (l & 7)) << 3;
    const int co1 = ((4 + (l >> 4)) ^ (l & 7)) << 3;

    const bf16_t* rbA00 = &sA[0][(wr * 128 + (l & 15)) * 64 + co0];
    const bf16_t* rbA01 = &sA[0][(wr * 128 + (l & 15)) * 64 + co1];
    const bf16_t* rbA10 = &sA[1][(wr * 128 + (l & 15)) * 64 + co0];
    const bf16_t* rbA11 = &sA[1][(wr * 128 + (l & 15)) * 64 + co1];
    const bf16_t* rbB00 = &sB[0][(wcn * 64 + (l & 15)) * 64 + co0];
    const bf16_t* rbB01 = &sB[0][(wcn * 64 + (l & 15)) * 64 + co1];
    const bf16_t* rbB10 = &sB[1][(wcn * 64 + (l & 15)) * 64 + co0];
    const bf16_t* rbB11 = &sB[1][(wcn * 64 + (l & 15)) * 64 + co1];

    STAGE8(0, 0);

    for (int it = 0; it < NI; ++it) {
        const int v = 2 * it + 1;
        asm volatile("s_waitcnt lgkmcnt(0)" ::: "memory");
        __builtin_amdgcn_s_barrier();
        STAGE8((long)v * 64, 1);
        asm volatile("s_waitcnt vmcnt(8)" ::: "memory");
        __builtin_amdgcn_s_barrier();
        COMPUTE(rbA00, rbA01, rbB00, rbB01);
        asm volatile("s_waitcnt lgkmcnt(0)" ::: "memory");
        __builtin_amdgcn_s_barrier();
        if (v + 1 < NT) {
            STAGE8((long)(v + 1) * 64, 0);
            asm volatile("s_waitcnt vmcnt(8)" ::: "memory");
        } else {
            asm volatile("s_waitcnt vmcnt(0)" ::: "memory");
        }
        __builtin_amdgcn_s_barrier();
        COMPUTE(rbA10, rbA11, rbB10, rbB11);
    }

#pragma unroll
    for (int mi = 0; mi < 8; mi++) {
#pragma unroll
        for (int nj = 0; nj < 4; nj++) {
            f32x4 vv = acc[mi][nj];
            const long col   = n0 + wcn * 64 + nj * 16 + (l & 15);
            const long row0r = m0 + wr * 128 + mi * 16 + ((l >> 4) * 4);
#pragma unroll
            for (int e = 0; e < 4; e++) {
                const long row = row0r + e;
                const long idx = row * (long)ldc + col + (long)blockIdx.z * sCz;
                const float val = vv[e];
                if constexpr (EPI == EPI_F32) {
                    ((float*)Cout)[idx] = val;
                } else if constexpr (EPI == EPI_BF16) {
                    ((bf16_t*)Cout)[idx] = (bf16_t)val;
                } else if constexpr (EPI == EPI_RES) {
                    const int b = (int)(row / rowsPerB);
                    ((float*)Cout)[idx] = res[row * (long)ldc + col] + val * gate[(long)b * gateStride + col];
                } else if constexpr (EPI == EPI_GELU) {
                    const float gl = 0.5f * val * (1.f + tanhf(0.7978845608f * (val + 0.044715f * val * val * val)));
                    ((bf16_t*)Cout)[idx] = (bf16_t)gl;
                } else if constexpr (EPI == EPI_MUL) {
                    ((bf16_t*)Cout)[idx] = (bf16_t)((float)aux[idx] * val);
                }
            }
        }
    }
#undef SCA
#undef SCB
}

// out = res + (P[z=0] + P[z=1]) * gate   (split-K combine, fp32, float4)
__global__ __launch_bounds__(256)
void combine_splitk(const float* __restrict__ P, const float* __restrict__ res,
                    const float* __restrict__ gate, float* __restrict__ out,
                    int D, int T, int gateStride, long zstride, long n4)
{
    for (long i4 = (long)blockIdx.x * 256 + threadIdx.x; i4 < n4; i4 += (long)gridDim.x * 256) {
        const long i = i4 * 4;
        const float4 p0 = *(const float4*)(P + i);
        const float4 p1 = *(const float4*)(P + i + zstride);
        const float4 xv = *(const float4*)(res + i);
        const long row = i / D;
        const int  b   = (int)(row / T);
        const int  col = (int)(i - row * D);
        const float* gp = gate + (long)b * gateStride + col;
        float4 r;
        r.x = xv.x + (p0.x + p1.x) * gp[0];
        r.y = xv.y + (p0.y + p1.y) * gp[1];
        r.z = xv.z + (p0.z + p1.z) * gp[2];
        r.w = xv.w + (p0.w + p1.w) * gp[3];
        *(float4*)(out + i) = r;
    }
}

// ---------------------------------------------------------------------------
// 128x128 m97-structure GEMM (QK / PV: causal block-skip / kend logic)
// ---------------------------------------------------------------------------
template<int EPI, int CAUSAL>
__global__ __launch_bounds__(256)
void gemm_bt(const bf16_t* __restrict__ A, const bf16_t* __restrict__ Bt,
             void* __restrict__ Cout,
             int M, int N, int Kd, int lda, int ldb, int ldc,
             long sAz, long sBz, long sCz,
             const float* __restrict__ res, const float* __restrict__ gate,
             int gateStride, int rowsPerB, const bf16_t* __restrict__ aux)
{
    const int tid = threadIdx.x;
    const int l   = tid & 63;
    const int w   = tid >> 6;
    const int wr  = w >> 1, wc = w & 1;
    const long m0 = (long)blockIdx.y * 128;
    const long n0 = (long)blockIdx.x * 128;
    const int  z  = blockIdx.z;

    if constexpr (CAUSAL == 1) {
        if (n0 > m0 + 127) return;
    }
    int kend = Kd;
    if constexpr (CAUSAL == 2) {
        const int kc = (int)m0 + 128;
        kend = kc < Kd ? kc : Kd;
    }

    A  += (long)z * sAz;
    Bt += (long)z * sBz;

    __shared__ bf16_t As[128 * 32];
    __shared__ bf16_t Bs[128 * 32];

    const int srow = w * 16 + (l >> 2);
    const int scol = (l & 3) * 8;
    const bf16_t* Ag = A  + (m0 + srow) * (long)lda + scol;
    const bf16_t* Bg = Bt + (n0 + srow) * (long)ldb + scol;

    bf16_t* ldsA = As + w * 512;
    bf16_t* ldsB = Bs + w * 512;

    f32x4 acc[16];
    const f32x4 fz = {0.f, 0.f, 0.f, 0.f};
#pragma unroll
    for (int i = 0; i < 16; i++) acc[i] = fz;

    for (int k0 = 0; k0 < kend; k0 += 32) {
        gload16(Ag + k0,                  ldsA);
        gload16(Ag + k0 + 64 * (long)lda, ldsA + 2048);
        gload16(Bg + k0,                  ldsB);
        gload16(Bg + k0 + 64 * (long)ldb, ldsB + 2048);
        __syncthreads();

        bf16x8 af[4], bfr[4];
#pragma unroll
        for (int f = 0; f < 4; f++) {
            af[f]  = *(const bf16x8*)(As + (wr * 64 + f * 16 + (l & 15)) * 32 + (l >> 4) * 8);
            bfr[f] = *(const bf16x8*)(Bs + (wc * 64 + f * 16 + (l & 15)) * 32 + (l >> 4) * 8);
        }
#pragma unroll
        for (int i = 0; i < 4; i++)
#pragma unroll
            for (int j = 0; j < 4; j++)
                acc[i * 4 + j] = __builtin_amdgcn_mfma_f32_16x16x32_bf16(af[i], bfr[j], acc[i * 4 + j], 0, 0, 0);
        __syncthreads();
    }

#pragma unroll
    for (int i = 0; i < 4; i++) {
#pragma unroll
        for (int j = 0; j < 4; j++) {
            f32x4 v = acc[i * 4 + j];
            const long col  = n0 + wc * 64 + j * 16 + (l & 15);
            const long row0 = m0 + wr * 64 + i * 16 + ((l >> 4) * 4);
#pragma unroll
            for (int e = 0; e < 4; e++) {
                const long row = row0 + e;
                const long idx = row * (long)ldc + col + (long)z * sCz;
                const float val = v[e];
                if constexpr (EPI == EPI_F32) {
                    ((float*)Cout)[idx] = val;
                } else if constexpr (EPI == EPI_BF16) {
                    ((bf16_t*)Cout)[idx] = (bf16_t)val;
                } else if constexpr (EPI == EPI_RES) {
                    const int b = (int)(row / rowsPerB);
                    ((float*)Cout)[idx] = res[row * (long)ldc + col] + val * gate[(long)b * gateStride + col];
                } else if constexpr (EPI == EPI_GELU) {
                    const float gl = 0.5f * val * (1.f + tanhf(0.7978845608f * (val + 0.044715f * val * val * val)));
                    ((bf16_t*)Cout)[idx] = (bf16_t)gl;
                } else {
                    ((bf16_t*)Cout)[idx] = (bf16_t)((float)aux[idx] * val);
                }
            }
        }
    }
}

// fp32 [R,C] -> bf16 [C,R] transpose (batched via blockIdx.z)
__global__ __launch_bounds__(256)
void transpose_f2b(const float* __restrict__ in, bf16_t* __restrict__ out,
                   int R, int C, long inStride, long outStride)
{
    __shared__ float tile[32][33];
    in  += (long)blockIdx.z * inStride;
    out += (long)blockIdx.z * outStride;
    const int c0 = blockIdx.x * 32, r0 = blockIdx.y * 32;
    const int tx = threadIdx.x, ty = threadIdx.y;
#pragma unroll
    for (int i = 0; i < 4; i++)
        tile[ty + i * 8][tx] = in[(long)(r0 + ty + i * 8) * C + c0 + tx];
    __syncthreads();
#pragma unroll
    for (int i = 0; i < 4; i++)
        out[(long)(c0 + ty + i * 8) * R + r0 + tx] = (bf16_t)tile[tx][ty + i * 8];
}

// mod = cond @ Wmod + bmod, two-stage K-split (deterministic)
__global__ __launch_bounds__(256)
void modk_part(const float* __restrict__ cond, const float* __restrict__ W,
               float* __restrict__ part, int D3, int KS)
{
    const int j = blockIdx.x * 256 + threadIdx.x;
    const int b = blockIdx.y;
    const int z = blockIdx.z;
    const float* cb = cond + (long)b * (KS * gridDim.z);
    float s = 0.f;
    const int d0 = z * KS;
#pragma unroll 4
    for (int d = d0; d < d0 + KS; d++) s += cb[d] * W[(long)d * D3 + j];
    part[((long)z * gridDim.y + b) * D3 + j] = s;
}

__global__ __launch_bounds__(256)
void modk_reduce(const float* __restrict__ part, const float* __restrict__ bvec,
                 float* __restrict__ mod, int D3, int NZ)
{
    const int j = blockIdx.x * 256 + threadIdx.x;
    const int b = blockIdx.y;
    float s = bvec[j];
    for (int z = 0; z < NZ; z++) s += part[((long)z * gridDim.y + b) * D3 + j];
    mod[(long)b * D3 + j] = s;
}

// RMSNorm (fp32) + AdaLN scale/shift -> bf16.  One block per row, D=2048.
__global__ __launch_bounds__(256)
void rmsnorm_adaln(const float* __restrict__ xin, const float* __restrict__ mod,
                   bf16_t* __restrict__ out, int D, int T, int D3)
{
    const long row = blockIdx.x;
    const int  b   = (int)(row / T);
    const int  tid = threadIdx.x;
    const float4* x4 = (const float4*)(xin + row * (long)D);
    const float4 v0 = x4[tid], v1 = x4[tid + 256];
    float ss = v0.x * v0.x + v0.y * v0.y + v0.z * v0.z + v0.w * v0.w
             + v1.x * v1.x + v1.y * v1.y + v1.z * v1.z + v1.w * v1.w;
    for (int o = 32; o; o >>= 1) ss += __shfl_down(ss, o, 64);
    __shared__ float red[4];
    if ((tid & 63) == 0) red[tid >> 6] = ss;
    __syncthreads();
    ss = red[0] + red[1] + red[2] + red[3];
    const float rs = rsqrtf(ss / (float)D + 1e-6f);
    const float* sc = mod + (long)b * D3;
    const float* sh = sc + D;
    const float4 s0 = ((const float4*)sc)[tid], s1 = ((const float4*)sc)[tid + 256];
    const float4 h0 = ((const float4*)sh)[tid], h1 = ((const float4*)sh)[tid + 256];
    bf16_t* orow = out + row * (long)D;
    orow[tid * 4 + 0]         = (bf16_t)(v0.x * rs * (1.f + s0.x) + h0.x);
    orow[tid * 4 + 1]         = (bf16_t)(v0.y * rs * (1.f + s0.y) + h0.y);
    orow[tid * 4 + 2]         = (bf16_t)(v0.z * rs * (1.f + s0.z) + h0.z);
    orow[tid * 4 + 3]         = (bf16_t)(v0.w * rs * (1.f + s0.w) + h0.w);
    orow[(tid + 256) * 4 + 0] = (bf16_t)(v1.x * rs * (1.f + s1.x) + h1.x);
    orow[(tid + 256) * 4 + 1] = (bf16_t)(v1.y * rs * (1.f + s1.y) + h1.y);
    orow[(tid + 256) * 4 + 2] = (bf16_t)(v1.z * rs * (1.f + s1.z) + h1.z);
    orow[(tid + 256) * 4 + 3] = (bf16_t)(v1.w * rs * (1.f + s1.w) + h1.w);
}

// RoPE on q (+ H^-0.5 scale), [BT,ldq] bf16 -> [B,N,T,H] bf16
__global__ __launch_bounds__(128)
void rope_q(const bf16_t* __restrict__ qp, const float* __restrict__ positions,
            bf16_t* __restrict__ qo, int T, int ldq, int H)
{
    const int t = blockIdx.x, n = blockIdx.y, b = blockIdx.z;
    const int i = threadIdx.x;
    const long in0 = ((long)(b * T + t)) * ldq + n * H;
    const float x1 = (float)qp[in0 + i];
    const float x2 = (float)qp[in0 + i + 128];
    const float pos = positions[b * T + t];
    const float inv = expf(-9.210340371976184f * (float)i / 128.f);
    float s, c;
    sincosf(pos * inv, &s, &c);
    const float scl = 0.0625f;
    const long out0 = (((long)(b * 8 + n)) * T + t) * H;
    qo[out0 + i]       = (bf16_t)((x1 * c - x2 * s) * scl);
    qo[out0 + i + 128] = (bf16_t)((x2 * c + x1 * s) * scl);
}

// RoPE on k + transpose v.  kvp: [BT][ldkv] bf16 (cols 0..255 k, 256..511 v)
__global__ __launch_bounds__(128)
void rope_kv(const bf16_t* __restrict__ kvp, const float* __restrict__ positions,
             bf16_t* __restrict__ ko, bf16_t* __restrict__ vt, int T, int H, int S, int ldkv)
{
    const int t = blockIdx.x, b = blockIdx.y;
    const int i = threadIdx.x;
    const long in0 = ((long)(b * T + t)) * ldkv;
    const float k1 = (float)kvp[in0 + i];
    const float k2 = (float)kvp[in0 + i + 128];
    const float pos = positions[b * T + t];
    const float inv = expf(-9.210340371976184f * (float)i / 128.f);
    float s, c;
    sincosf(pos * inv, &s, &c);
    const long ko0 = ((long)(b * T + t)) * H;
    ko[ko0 + i]       = (bf16_t)(k1 * c - k2 * s);
    ko[ko0 + i + 128] = (bf16_t)(k2 * c + k1 * s);
    vt[((long)b * H + i) * S + t]       = kvp[in0 + 256 + i];
    vt[((long)b * H + i + 128) * S + t] = kvp[in0 + 256 + i + 128];
}

// causal mask + softmax over rows of scores [G,T,S] fp32 -> probs bf16.
__global__ __launch_bounds__(256)
void softmax_causal(const float* __restrict__ sc, bf16_t* __restrict__ pr, int T, int S)
{
    const int t = blockIdx.x, g = blockIdx.y;
    const long row = (long)g * T + t;
    const float* srow = sc + row * S;
    bf16_t* prow = pr + row * S;
    const int tid = threadIdx.x;
    const int limit = t | 127;
    const int nch = (limit >> 8) + 1;
    float vals[8];
    float mx = -3.4e38f;
    for (int i = 0; i < nch; i++) {
        const int s = i * 256 + tid;
        const float v = (s <= t) ? srow[s] : -3.4e38f;
        vals[i] = v;
        mx = fmaxf(mx, v);
    }
    for (int o = 32; o; o >>= 1) mx = fmaxf(mx, __shfl_down(mx, o, 64));
    __shared__ float red[4];
    if ((tid & 63) == 0) red[tid >> 6] = mx;
    __syncthreads();
    mx = fmaxf(fmaxf(red[0], red[1]), fmaxf(red[2], red[3]));
    __syncthreads();
    float sum = 0.f;
    for (int i = 0; i < nch; i++) {
        const int s = i * 256 + tid;
        const float e = (s <= t) ? __expf(vals[i] - mx) : 0.f;
        vals[i] = e;
        sum += e;
    }
    for (int o = 32; o; o >>= 1) sum += __shfl_down(sum, o, 64);
    if ((tid & 63) == 0) red[tid >> 6] = sum;
    __syncthreads();
    sum = red[0] + red[1] + red[2] + red[3];
    const float invs = 1.f / sum;
    for (int i = 0; i < nch; i++)
        prow[i * 256 + tid] = (bf16_t)(vals[i] * invs);
}

extern "C" void kernel_launch(void* const* d_in, const int* in_sizes, int n_in,
                              void* d_out, int out_size, void* d_ws, size_t ws_size,
                              hipStream_t stream)
{
    const float* x      = (const float*)d_in[0];
    const float* pos    = (const float*)d_in[1];
    const float* cond   = (const float*)d_in[3];
    const float* Wmod_a = (const float*)d_in[4];
    const float* bmod_a = (const float*)d_in[5];
    const float* Wq     = (const float*)d_in[6];
    const float* Wkv    = (const float*)d_in[7];
    const float* Wo     = (const float*)d_in[8];
    const float* Wmod_f = (const float*)d_in[9];
    const float* bmod_f = (const float*)d_in[10];
    const float* Wg     = (const float*)d_in[11];
    const float* Wl     = (const float*)d_in[12];

    constexpr int  Bb = 2, T = 2048, D = 2048, F = 16384, Nh = 8, H = 256;
    constexpr int  NH = 2048, S = 2048, G = 8, BT = 4096, D3 = 6144;
    constexpr int  KSLICE = 64, NZ = D / KSLICE;
    constexpr int  NQKV = 2560;   // fused Q(2048) + K(256) + V(256)

    char* ws = (char*)d_ws;
    size_t off = 0;
    auto alloc = [&](size_t bytes) { char* p = ws + off; off += bytes; return p; };

    bf16_t* WQT  = (bf16_t*)alloc((size_t)NH * D * 2);      // rows 0-2047
    bf16_t* WKVT = (bf16_t*)alloc((size_t)512 * D * 2);     // rows 2048-2559 (contiguous)
    bf16_t* WOT  = (bf16_t*)alloc((size_t)D * NH * 2);
    bf16_t* WGT  = (bf16_t*)alloc((size_t)2 * F * D * 2);
    bf16_t* WLT  = (bf16_t*)alloc((size_t)D * F * 2);
    float*  MODA = (float*)alloc((size_t)Bb * D3 * 4);
    float*  MODF = (float*)alloc((size_t)Bb * D3 * 4);
    float*  PART = (float*)alloc((size_t)NZ * Bb * D3 * 4);
    bf16_t* NA   = (bf16_t*)alloc((size_t)BT * D * 2);
    bf16_t* QKVP = (bf16_t*)alloc((size_t)BT * NQKV * 2);
    bf16_t* Qr   = (bf16_t*)alloc((size_t)Bb * Nh * T * H * 2);
    bf16_t* Kr   = (bf16_t*)alloc((size_t)Bb * T * H * 2);
    bf16_t* VT   = (bf16_t*)alloc((size_t)Bb * H * S * 2);
    bf16_t* ENC  = (bf16_t*)alloc((size_t)BT * NH * 2);
    float*  X1   = (float*)alloc((size_t)BT * D * 4);
    bf16_t* NF   = (bf16_t*)alloc((size_t)BT * D * 2);
    const size_t scBytes = (size_t)G * T * S * 4;   // 128 MB
    const size_t prBytes = (size_t)G * T * S * 2;   //  64 MB
    const size_t hBytes  = (size_t)BT * F * 2;      // 128 MB
    const size_t bigBytes = (scBytes + prBytes > hBytes) ? (scBytes + prBytes) : hBytes;
    char* big = alloc(bigBytes);
    float*  SC = (float*)big;
    bf16_t* PR = (bf16_t*)(big + scBytes);
    bf16_t* Hb = (bf16_t*)big;                       // aliases SC/PR
    float*  PARTK = (float*)(big + hBytes);          // 64 MB tail (PR dead by then)
    (void)ws_size; (void)in_sizes; (void)n_in; (void)out_size;

    const dim3 tb(32, 8);
    transpose_f2b<<<dim3(H / 32, D / 32, 8), tb, 0, stream>>>(Wq,  WQT,  D,  H, (long)D * H, (long)H * D);
    transpose_f2b<<<dim3(H / 32, D / 32, 2), tb, 0, stream>>>(Wkv, WKVT, D,  H, (long)D * H, (long)H * D);
    transpose_f2b<<<dim3(D / 32, NH / 32, 1), tb, 0, stream>>>(Wo, WOT, NH,  D, 0, 0);
    transpose_f2b<<<dim3(F / 32, D / 32, 2), tb, 0, stream>>>(Wg,  WGT,  D,  F, (long)D * F, (long)F * D);
    transpose_f2b<<<dim3(D / 32, F / 32, 1), tb, 0, stream>>>(Wl,  WLT,  F,  D, 0, 0);
    modk_part<<<dim3(D3 / 256, Bb, NZ), 256, 0, stream>>>(cond, Wmod_a, PART, D3, KSLICE);
    modk_reduce<<<dim3(D3 / 256, Bb), 256, 0, stream>>>(PART, bmod_a, MODA, D3, NZ);
    modk_part<<<dim3(D3 / 256, Bb, NZ), 256, 0, stream>>>(cond, Wmod_f, PART, D3, KSLICE);
    modk_reduce<<<dim3(D3 / 256, Bb), 256, 0, stream>>>(PART, bmod_f, MODF, D3, NZ);
    rmsnorm_adaln<<<BT, 256, 0, stream>>>(x, MODA, NA, D, T, D3);
    // fused Q+KV projection (N=2560, 256^2 pipelined)
    gemma<EPI_BF16><<<dim3(NQKV / 256, BT / 256, 1), 512, 0, stream>>>(
        NA, WQT, QKVP, D, D, D, NQKV, 0, nullptr, nullptr, 0, 0, nullptr);
    rope_q<<<dim3(T, Nh, Bb), 128, 0, stream>>>(QKVP, pos, Qr, T, NQKV, H);
    rope_kv<<<dim3(T, Bb), 128, 0, stream>>>(QKVP + NH, pos, Kr, VT, T, H, S, NQKV);
    for (int b = 0; b < Bb; b++) {
        gemm_bt<EPI_F32, 1><<<dim3(S / 128, T / 128, G), 256, 0, stream>>>(
            Qr + (long)b * Nh * T * H, Kr + (long)b * T * H, SC,
            T, S, H, H, H, S, (long)T * H, 0, (long)T * S, nullptr, nullptr, 0, 0, nullptr);
        softmax_causal<<<dim3(T, G), 256, 0, stream>>>(SC, PR, T, S);
        gemm_bt<EPI_BF16, 2><<<dim3(H / 128, T / 128, G), 256, 0, stream>>>(
            PR, VT + (long)b * H * S, ENC + (long)b * T * NH,
            T, H, S, S, S, NH, (long)T * S, 0, (long)H, nullptr, nullptr, 0, 0, nullptr);
    }
    // Wo projection, split-K=2 (full GPU) + combine with gated residual -> X1
    gemma<EPI_F32><<<dim3(D / 256, BT / 256, 2), 512, 0, stream>>>(
        ENC, WOT, PARTK, NH / 2, NH, NH, D, (long)BT * D, nullptr, nullptr, 0, 0, nullptr);
    combine_splitk<<<2048, 256, 0, stream>>>(
        PARTK, x, MODA + 2 * D, X1, D, T, D3, (long)BT * D, (long)BT * D / 4);
    rmsnorm_adaln<<<BT, 256, 0, stream>>>(X1, MODF, NF, D, T, D3);
    // FFN up: h0 = gelu(n@Wg0); h = h0 * (n@Wg1) in-place
    gemma<EPI_GELU><<<dim3(F / 256, BT / 256, 1), 512, 0, stream>>>(
        NF, WGT, Hb, D, D, D, F, 0, nullptr, nullptr, 0, 0, nullptr);
    gemma<EPI_MUL><<<dim3(F / 256, BT / 256, 1), 512, 0, stream>>>(
        NF, WGT + (long)F * D, Hb, D, D, D, F, 0, nullptr, nullptr, 0, 0, Hb);
    // FFN down: split-K=2 partials + fused combine -> out
    gemma<EPI_F32><<<dim3(D / 256, BT / 256, 2), 512, 0, stream>>>(
        Hb, WLT, PARTK, F / 2, F, F, D, (long)BT * D, nullptr, nullptr, 0, 0, nullptr);
    combine_splitk<<<2048, 256, 0, stream>>>(
        PARTK, X1, MODF + 2 * D, (float*)d_out, D, T, D3, (long)BT * D, (long)BT * D / 4);
}

// Round 14
// 1469.770 us; speedup vs baseline: 1.1836x; 1.0382x over previous
//
#include <hip/hip_runtime.h>
#include <hip/hip_bf16.h>

typedef __bf16 bf16_t;
typedef __bf16 bf16x8 __attribute__((ext_vector_type(8)));
typedef float  f32x4  __attribute__((ext_vector_type(4)));

#define DEV static __device__ __forceinline__

DEV void gload16(const bf16_t* g, bf16_t* l) {
    __builtin_amdgcn_global_load_lds(
        (const __attribute__((address_space(1))) void*)g,
        (__attribute__((address_space(3))) void*)l, 16, 0, 0);
}

enum { EPI_F32 = 0, EPI_BF16 = 1, EPI_RES = 2, EPI_GELU = 3, EPI_MUL = 4 };

#define G_MFMA(d, a, b) d = __builtin_amdgcn_mfma_f32_16x16x32_bf16(a, b, d, 0, 0, 0)

// ---------------------------------------------------------------------------
// gemma: 256x256-tile, BK=64, 8 waves (2Mx4N) pipelined GEMM (r11 structure,
// best measured).  Zero-conflict LDS swizzle; precomputed bases; split-K via
// blockIdx.z.  Requires M,N % 256 == 0, Kd % 128 == 0.
// ---------------------------------------------------------------------------
#define COMPUTE(AB0, AB1, BB0, BB1)                                           \
  { bf16x8 aF[8], bF[4];                                                      \
    _Pragma("unroll") for (int m8 = 0; m8 < 8; m8++)                          \
      aF[m8] = *(const bf16x8*)(AB0 + (m8 >> 2) * 4096 + (m8 & 3) * 1024);    \
    _Pragma("unroll") for (int nj = 0; nj < 4; nj++)                          \
      bF[nj] = *(const bf16x8*)(BB0 + nj * 1024);                             \
    _Pragma("unroll") for (int m8 = 0; m8 < 8; m8++)                          \
      _Pragma("unroll") for (int nj = 0; nj < 4; nj++)                        \
        G_MFMA(acc[m8][nj], aF[m8], bF[nj]);                                  \
    _Pragma("unroll") for (int m8 = 0; m8 < 8; m8++)                          \
      aF[m8] = *(const bf16x8*)(AB1 + (m8 >> 2) * 4096 + (m8 & 3) * 1024);    \
    _Pragma("unroll") for (int nj = 0; nj < 4; nj++)                          \
      bF[nj] = *(const bf16x8*)(BB1 + nj * 1024);                             \
    _Pragma("unroll") for (int m8 = 0; m8 < 8; m8++)                          \
      _Pragma("unroll") for (int nj = 0; nj < 4; nj++)                        \
        G_MFMA(acc[m8][nj], aF[m8], bF[nj]);                                  \
  }

#define STAGE8(kt, bi)                                                        \
  { SCA(kt, bi, 0); SCA(kt, bi, 1); SCA(kt, bi, 2); SCA(kt, bi, 3);           \
    SCB(kt, bi, 0); SCB(kt, bi, 1); SCB(kt, bi, 2); SCB(kt, bi, 3); }

template<int EPI>
__global__ __launch_bounds__(512, 1)
void gemma(const bf16_t* __restrict__ A, const bf16_t* __restrict__ Bt,
           void* __restrict__ Cout, int Kd, int lda, int ldb, int ldc,
           long sCz,
           const float* __restrict__ res, const float* __restrict__ gate,
           int gateStride, int rowsPerB, const bf16_t* __restrict__ aux)
{
    const int nbx = gridDim.x;
    const int nwg = nbx * gridDim.y;
    int lin = blockIdx.y * nbx + blockIdx.x;
    const int q8 = nwg >> 3, r8 = nwg & 7;
    const int xcd = lin & 7, oo = lin >> 3;
    lin = (xcd < r8 ? xcd * (q8 + 1) : r8 * (q8 + 1) + (xcd - r8) * q8) + oo;
    const long m0 = (long)(lin / nbx) * 256;
    const long n0 = (long)(lin % nbx) * 256;
    const long kb = (long)blockIdx.z * Kd;

    const int tid = threadIdx.x;
    const int l   = tid & 63;
    const int w   = tid >> 6;
    const int wr  = w >> 2;
    const int wcn = w & 3;

    __shared__ bf16_t sA[2][16384];
    __shared__ bf16_t sB[2][16384];

    const long sgc = (long)(((l & 7) ^ (l >> 3)) << 3);
    const int NT = Kd >> 6;
    const int NI = NT >> 1;

    const bf16_t* pA0 = A + (m0 + 0 * 64 + w * 8 + (l >> 3)) * (long)lda + kb + sgc;
    const bf16_t* pA1 = A + (m0 + 1 * 64 + w * 8 + (l >> 3)) * (long)lda + kb + sgc;
    const bf16_t* pA2 = A + (m0 + 2 * 64 + w * 8 + (l >> 3)) * (long)lda + kb + sgc;
    const bf16_t* pA3 = A + (m0 + 3 * 64 + w * 8 + (l >> 3)) * (long)lda + kb + sgc;
    const bf16_t* pB0 = Bt + (n0 + 0 * 64 + w * 8 + (l >> 3)) * (long)ldb + kb + sgc;
    const bf16_t* pB1 = Bt + (n0 + 1 * 64 + w * 8 + (l >> 3)) * (long)ldb + kb + sgc;
    const bf16_t* pB2 = Bt + (n0 + 2 * 64 + w * 8 + (l >> 3)) * (long)ldb + kb + sgc;
    const bf16_t* pB3 = Bt + (n0 + 3 * 64 + w * 8 + (l >> 3)) * (long)ldb + kb + sgc;

#define SCA(kt, bi, c) gload16(pA##c + (kt), &sA[bi][(c) * 4096 + w * 512])
#define SCB(kt, bi, c) gload16(pB##c + (kt), &sB[bi][(c) * 4096 + w * 512])

    f32x4 acc[8][4];
#pragma unroll
    for (int i = 0; i < 8; i++)
#pragma unroll
        for (int j = 0; j < 4; j++) acc[i][j] = f32x4{0.f, 0.f, 0.f, 0.f};

    const int co0 = ((l >> 4) ^ (l & 7)) << 3;
    const int co1 = ((4 + (l >> 4)) ^ (l & 7)) << 3;

    const bf16_t* rbA00 = &sA[0][(wr * 128 + (l & 15)) * 64 + co0];
    const bf16_t* rbA01 = &sA[0][(wr * 128 + (l & 15)) * 64 + co1];
    const bf16_t* rbA10 = &sA[1][(wr * 128 + (l & 15)) * 64 + co0];
    const bf16_t* rbA11 = &sA[1][(wr * 128 + (l & 15)) * 64 + co1];
    const bf16_t* rbB00 = &sB[0][(wcn * 64 + (l & 15)) * 64 + co0];
    const bf16_t* rbB01 = &sB[0][(wcn * 64 + (l & 15)) * 64 + co1];
    const bf16_t* rbB10 = &sB[1][(wcn * 64 + (l & 15)) * 64 + co0];
    const bf16_t* rbB11 = &sB[1][(wcn * 64 + (l & 15)) * 64 + co1];

    STAGE8(0, 0);

    for (int it = 0; it < NI; ++it) {
        const int v = 2 * it + 1;
        asm volatile("s_waitcnt lgkmcnt(0)" ::: "memory");
        __builtin_amdgcn_s_barrier();
        STAGE8((long)v * 64, 1);
        asm volatile("s_waitcnt vmcnt(8)" ::: "memory");
        __builtin_amdgcn_s_barrier();
        COMPUTE(rbA00, rbA01, rbB00, rbB01);
        asm volatile("s_waitcnt lgkmcnt(0)" ::: "memory");
        __builtin_amdgcn_s_barrier();
        if (v + 1 < NT) {
            STAGE8((long)(v + 1) * 64, 0);
            asm volatile("s_waitcnt vmcnt(8)" ::: "memory");
        } else {
            asm volatile("s_waitcnt vmcnt(0)" ::: "memory");
        }
        __builtin_amdgcn_s_barrier();
        COMPUTE(rbA10, rbA11, rbB10, rbB11);
    }

#pragma unroll
    for (int mi = 0; mi < 8; mi++) {
#pragma unroll
        for (int nj = 0; nj < 4; nj++) {
            f32x4 vv = acc[mi][nj];
            const long col   = n0 + wcn * 64 + nj * 16 + (l & 15);
            const long row0r = m0 + wr * 128 + mi * 16 + ((l >> 4) * 4);
#pragma unroll
            for (int e = 0; e < 4; e++) {
                const long row = row0r + e;
                const long idx = row * (long)ldc + col + (long)blockIdx.z * sCz;
                const float val = vv[e];
                if constexpr (EPI == EPI_F32) {
                    ((float*)Cout)[idx] = val;
                } else if constexpr (EPI == EPI_BF16) {
                    ((bf16_t*)Cout)[idx] = (bf16_t)val;
                } else if constexpr (EPI == EPI_RES) {
                    const int b = (int)(row / rowsPerB);
                    ((float*)Cout)[idx] = res[row * (long)ldc + col] + val * gate[(long)b * gateStride + col];
                } else if constexpr (EPI == EPI_GELU) {
                    const float gl = 0.5f * val * (1.f + tanhf(0.7978845608f * (val + 0.044715f * val * val * val)));
                    ((bf16_t*)Cout)[idx] = (bf16_t)gl;
                } else if constexpr (EPI == EPI_MUL) {
                    ((bf16_t*)Cout)[idx] = (bf16_t)((float)aux[idx] * val);
                }
            }
        }
    }
#undef SCA
#undef SCB
}

// out = res + (P[z=0] + P[z=1]) * gate   (split-K combine, fp32, float4)
__global__ __launch_bounds__(256)
void combine_splitk(const float* __restrict__ P, const float* __restrict__ res,
                    const float* __restrict__ gate, float* __restrict__ out,
                    int D, int T, int gateStride, long zstride, long n4)
{
    for (long i4 = (long)blockIdx.x * 256 + threadIdx.x; i4 < n4; i4 += (long)gridDim.x * 256) {
        const long i = i4 * 4;
        const float4 p0 = *(const float4*)(P + i);
        const float4 p1 = *(const float4*)(P + i + zstride);
        const float4 xv = *(const float4*)(res + i);
        const long row = i / D;
        const int  b   = (int)(row / T);
        const int  col = (int)(i - row * D);
        const float* gp = gate + (long)b * gateStride + col;
        float4 r;
        r.x = xv.x + (p0.x + p1.x) * gp[0];
        r.y = xv.y + (p0.y + p1.y) * gp[1];
        r.z = xv.z + (p0.z + p1.z) * gp[2];
        r.w = xv.w + (p0.w + p1.w) * gp[3];
        *(float4*)(out + i) = r;
    }
}

// ---------------------------------------------------------------------------
// 128x128 m97-structure GEMM for attention, z-batched over (b,g): z = b*8+g.
// A += z*sAz; Bt += (z>>3)*sBz; C offset = (z>>3)*sCz2 + (z&7)*sCz.
// CAUSAL: 1 = skip blocks above diagonal (QK^T), 2 = K-loop limited (PV)
// ---------------------------------------------------------------------------
template<int EPI, int CAUSAL>
__global__ __launch_bounds__(256)
void gemm_bt(const bf16_t* __restrict__ A, const bf16_t* __restrict__ Bt,
             void* __restrict__ Cout,
             int M, int N, int Kd, int lda, int ldb, int ldc,
             long sAz, long sBz, long sCz, long sCz2)
{
    const int tid = threadIdx.x;
    const int l   = tid & 63;
    const int w   = tid >> 6;
    const int wr  = w >> 1, wc = w & 1;
    const long m0 = (long)blockIdx.y * 128;
    const long n0 = (long)blockIdx.x * 128;
    const int  z  = blockIdx.z;

    if constexpr (CAUSAL == 1) {
        if (n0 > m0 + 127) return;
    }
    int kend = Kd;
    if constexpr (CAUSAL == 2) {
        const int kc = (int)m0 + 128;
        kend = kc < Kd ? kc : Kd;
    }

    A  += (long)z * sAz;
    Bt += (long)(z >> 3) * sBz;
    const long cOff = (long)(z >> 3) * sCz2 + (long)(z & 7) * sCz;

    __shared__ bf16_t As[128 * 32];
    __shared__ bf16_t Bs[128 * 32];

    const int srow = w * 16 + (l >> 2);
    const int scol = (l & 3) * 8;
    const bf16_t* Ag = A  + (m0 + srow) * (long)lda + scol;
    const bf16_t* Bg = Bt + (n0 + srow) * (long)ldb + scol;

    bf16_t* ldsA = As + w * 512;
    bf16_t* ldsB = Bs + w * 512;

    f32x4 acc[16];
    const f32x4 fz = {0.f, 0.f, 0.f, 0.f};
#pragma unroll
    for (int i = 0; i < 16; i++) acc[i] = fz;

    for (int k0 = 0; k0 < kend; k0 += 32) {
        gload16(Ag + k0,                  ldsA);
        gload16(Ag + k0 + 64 * (long)lda, ldsA + 2048);
        gload16(Bg + k0,                  ldsB);
        gload16(Bg + k0 + 64 * (long)ldb, ldsB + 2048);
        __syncthreads();

        bf16x8 af[4], bfr[4];
#pragma unroll
        for (int f = 0; f < 4; f++) {
            af[f]  = *(const bf16x8*)(As + (wr * 64 + f * 16 + (l & 15)) * 32 + (l >> 4) * 8);
            bfr[f] = *(const bf16x8*)(Bs + (wc * 64 + f * 16 + (l & 15)) * 32 + (l >> 4) * 8);
        }
#pragma unroll
        for (int i = 0; i < 4; i++)
#pragma unroll
            for (int j = 0; j < 4; j++)
                acc[i * 4 + j] = __builtin_amdgcn_mfma_f32_16x16x32_bf16(af[i], bfr[j], acc[i * 4 + j], 0, 0, 0);
        __syncthreads();
    }

#pragma unroll
    for (int i = 0; i < 4; i++) {
#pragma unroll
        for (int j = 0; j < 4; j++) {
            f32x4 v = acc[i * 4 + j];
            const long col  = n0 + wc * 64 + j * 16 + (l & 15);
            const long row0 = m0 + wr * 64 + i * 16 + ((l >> 4) * 4);
#pragma unroll
            for (int e = 0; e < 4; e++) {
                const long row = row0 + e;
                const long idx = row * (long)ldc + col + cOff;
                ((bf16_t*)Cout)[idx] = (bf16_t)v[e];
            }
        }
    }
}

// fp32 [R,C] -> bf16 [C,R] transpose (batched via blockIdx.z)
__global__ __launch_bounds__(256)
void transpose_f2b(const float* __restrict__ in, bf16_t* __restrict__ out,
                   int R, int C, long inStride, long outStride)
{
    __shared__ float tile[32][33];
    in  += (long)blockIdx.z * inStride;
    out += (long)blockIdx.z * outStride;
    const int c0 = blockIdx.x * 32, r0 = blockIdx.y * 32;
    const int tx = threadIdx.x, ty = threadIdx.y;
#pragma unroll
    for (int i = 0; i < 4; i++)
        tile[ty + i * 8][tx] = in[(long)(r0 + ty + i * 8) * C + c0 + tx];
    __syncthreads();
#pragma unroll
    for (int i = 0; i < 4; i++)
        out[(long)(c0 + ty + i * 8) * R + r0 + tx] = (bf16_t)tile[tx][ty + i * 8];
}

// mod = cond @ Wmod + bmod, two-stage K-split (deterministic)
__global__ __launch_bounds__(256)
void modk_part(const float* __restrict__ cond, const float* __restrict__ W,
               float* __restrict__ part, int D3, int KS)
{
    const int j = blockIdx.x * 256 + threadIdx.x;
    const int b = blockIdx.y;
    const int z = blockIdx.z;
    const float* cb = cond + (long)b * (KS * gridDim.z);
    float s = 0.f;
    const int d0 = z * KS;
#pragma unroll 4
    for (int d = d0; d < d0 + KS; d++) s += cb[d] * W[(long)d * D3 + j];
    part[((long)z * gridDim.y + b) * D3 + j] = s;
}

__global__ __launch_bounds__(256)
void modk_reduce(const float* __restrict__ part, const float* __restrict__ bvec,
                 float* __restrict__ mod, int D3, int NZ)
{
    const int j = blockIdx.x * 256 + threadIdx.x;
    const int b = blockIdx.y;
    float s = bvec[j];
    for (int z = 0; z < NZ; z++) s += part[((long)z * gridDim.y + b) * D3 + j];
    mod[(long)b * D3 + j] = s;
}

// RMSNorm (fp32) + AdaLN scale/shift -> bf16.  One block per row, D=2048.
__global__ __launch_bounds__(256)
void rmsnorm_adaln(const float* __restrict__ xin, const float* __restrict__ mod,
                   bf16_t* __restrict__ out, int D, int T, int D3)
{
    const long row = blockIdx.x;
    const int  b   = (int)(row / T);
    const int  tid = threadIdx.x;
    const float4* x4 = (const float4*)(xin + row * (long)D);
    const float4 v0 = x4[tid], v1 = x4[tid + 256];
    float ss = v0.x * v0.x + v0.y * v0.y + v0.z * v0.z + v0.w * v0.w
             + v1.x * v1.x + v1.y * v1.y + v1.z * v1.z + v1.w * v1.w;
    for (int o = 32; o; o >>= 1) ss += __shfl_down(ss, o, 64);
    __shared__ float red[4];
    if ((tid & 63) == 0) red[tid >> 6] = ss;
    __syncthreads();
    ss = red[0] + red[1] + red[2] + red[3];
    const float rs = rsqrtf(ss / (float)D + 1e-6f);
    const float* sc = mod + (long)b * D3;
    const float* sh = sc + D;
    const float4 s0 = ((const float4*)sc)[tid], s1 = ((const float4*)sc)[tid + 256];
    const float4 h0 = ((const float4*)sh)[tid], h1 = ((const float4*)sh)[tid + 256];
    bf16_t* orow = out + row * (long)D;
    orow[tid * 4 + 0]         = (bf16_t)(v0.x * rs * (1.f + s0.x) + h0.x);
    orow[tid * 4 + 1]         = (bf16_t)(v0.y * rs * (1.f + s0.y) + h0.y);
    orow[tid * 4 + 2]         = (bf16_t)(v0.z * rs * (1.f + s0.z) + h0.z);
    orow[tid * 4 + 3]         = (bf16_t)(v0.w * rs * (1.f + s0.w) + h0.w);
    orow[(tid + 256) * 4 + 0] = (bf16_t)(v1.x * rs * (1.f + s1.x) + h1.x);
    orow[(tid + 256) * 4 + 1] = (bf16_t)(v1.y * rs * (1.f + s1.y) + h1.y);
    orow[(tid + 256) * 4 + 2] = (bf16_t)(v1.z * rs * (1.f + s1.z) + h1.z);
    orow[(tid + 256) * 4 + 3] = (bf16_t)(v1.w * rs * (1.f + s1.w) + h1.w);
}

// RoPE on q (+ H^-0.5 scale), [BT,ldq] bf16 -> [B,N,T,H] bf16
__global__ __launch_bounds__(128)
void rope_q(const bf16_t* __restrict__ qp, const float* __restrict__ positions,
            bf16_t* __restrict__ qo, int T, int ldq, int H)
{
    const int t = blockIdx.x, n = blockIdx.y, b = blockIdx.z;
    const int i = threadIdx.x;
    const long in0 = ((long)(b * T + t)) * ldq + n * H;
    const float x1 = (float)qp[in0 + i];
    const float x2 = (float)qp[in0 + i + 128];
    const float pos = positions[b * T + t];
    const float inv = expf(-9.210340371976184f * (float)i / 128.f);
    float s, c;
    sincosf(pos * inv, &s, &c);
    const float scl = 0.0625f;
    const long out0 = (((long)(b * 8 + n)) * T + t) * H;
    qo[out0 + i]       = (bf16_t)((x1 * c - x2 * s) * scl);
    qo[out0 + i + 128] = (bf16_t)((x2 * c + x1 * s) * scl);
}

// RoPE on k + transpose v.  kvp: [BT][ldkv] bf16 (cols 0..255 k, 256..511 v)
__global__ __launch_bounds__(128)
void rope_kv(const bf16_t* __restrict__ kvp, const float* __restrict__ positions,
             bf16_t* __restrict__ ko, bf16_t* __restrict__ vt, int T, int H, int S, int ldkv)
{
    const int t = blockIdx.x, b = blockIdx.y;
    const int i = threadIdx.x;
    const long in0 = ((long)(b * T + t)) * ldkv;
    const float k1 = (float)kvp[in0 + i];
    const float k2 = (float)kvp[in0 + i + 128];
    const float pos = positions[b * T + t];
    const float inv = expf(-9.210340371976184f * (float)i / 128.f);
    float s, c;
    sincosf(pos * inv, &s, &c);
    const long ko0 = ((long)(b * T + t)) * H;
    ko[ko0 + i]       = (bf16_t)(k1 * c - k2 * s);
    ko[ko0 + i + 128] = (bf16_t)(k2 * c + k1 * s);
    vt[((long)b * H + i) * S + t]       = kvp[in0 + 256 + i];
    vt[((long)b * H + i + 128) * S + t] = kvp[in0 + 256 + i + 128];
}

// causal mask + softmax, IN-PLACE over bf16 scores [16][T][S].
// Only columns [0, t|127] are read downstream (PV kend-clips).
__global__ __launch_bounds__(256)
void softmax_causal(bf16_t* __restrict__ sc, int T, int S)
{
    const int t = blockIdx.x, z = blockIdx.y;
    const long row = (long)z * T + t;
    bf16_t* srow = sc + row * S;
    const int tid = threadIdx.x;
    const int limit = t | 127;
    const int nch = (limit >> 8) + 1;
    float vals[8];
    float mx = -3.4e38f;
    for (int i = 0; i < nch; i++) {
        const int s = i * 256 + tid;
        const float v = (s <= t) ? (float)srow[s] : -3.4e38f;
        vals[i] = v;
        mx = fmaxf(mx, v);
    }
    for (int o = 32; o; o >>= 1) mx = fmaxf(mx, __shfl_down(mx, o, 64));
    __shared__ float red[4];
    if ((tid & 63) == 0) red[tid >> 6] = mx;
    __syncthreads();
    mx = fmaxf(fmaxf(red[0], red[1]), fmaxf(red[2], red[3]));
    __syncthreads();
    float sum = 0.f;
    for (int i = 0; i < nch; i++) {
        const int s = i * 256 + tid;
        const float e = (s <= t) ? __expf(vals[i] - mx) : 0.f;
        vals[i] = e;
        sum += e;
    }
    for (int o = 32; o; o >>= 1) sum += __shfl_down(sum, o, 64);
    if ((tid & 63) == 0) red[tid >> 6] = sum;
    __syncthreads();
    sum = red[0] + red[1] + red[2] + red[3];
    const float invs = 1.f / sum;
    for (int i = 0; i < nch; i++)
        srow[i * 256 + tid] = (bf16_t)(vals[i] * invs);
}

extern "C" void kernel_launch(void* const* d_in, const int* in_sizes, int n_in,
                              void* d_out, int out_size, void* d_ws, size_t ws_size,
                              hipStream_t stream)
{
    const float* x      = (const float*)d_in[0];
    const float* pos    = (const float*)d_in[1];
    const float* cond   = (const float*)d_in[3];
    const float* Wmod_a = (const float*)d_in[4];
    const float* bmod_a = (const float*)d_in[5];
    const float* Wq     = (const float*)d_in[6];
    const float* Wkv    = (const float*)d_in[7];
    const float* Wo     = (const float*)d_in[8];
    const float* Wmod_f = (const float*)d_in[9];
    const float* bmod_f = (const float*)d_in[10];
    const float* Wg     = (const float*)d_in[11];
    const float* Wl     = (const float*)d_in[12];

    constexpr int  Bb = 2, T = 2048, D = 2048, F = 16384, Nh = 8, H = 256;
    constexpr int  NH = 2048, S = 2048, BT = 4096, D3 = 6144;
    constexpr int  KSLICE = 64, NZ = D / KSLICE;
    constexpr int  NQKV = 2560;   // fused Q(2048) + K(256) + V(256)

    char* ws = (char*)d_ws;
    size_t off = 0;
    auto alloc = [&](size_t bytes) { char* p = ws + off; off += bytes; return p; };

    bf16_t* WQT  = (bf16_t*)alloc((size_t)NH * D * 2);      // rows 0-2047
    bf16_t* WKVT = (bf16_t*)alloc((size_t)512 * D * 2);     // rows 2048-2559 (contiguous)
    bf16_t* WOT  = (bf16_t*)alloc((size_t)D * NH * 2);
    bf16_t* WGT  = (bf16_t*)alloc((size_t)2 * F * D * 2);
    bf16_t* WLT  = (bf16_t*)alloc((size_t)D * F * 2);
    float*  MODA = (float*)alloc((size_t)Bb * D3 * 4);
    float*  MODF = (float*)alloc((size_t)Bb * D3 * 4);
    float*  PART = (float*)alloc((size_t)NZ * Bb * D3 * 4);
    bf16_t* NA   = (bf16_t*)alloc((size_t)BT * D * 2);
    bf16_t* QKVP = (bf16_t*)alloc((size_t)BT * NQKV * 2);
    bf16_t* Qr   = (bf16_t*)alloc((size_t)Bb * Nh * T * H * 2);
    bf16_t* Kr   = (bf16_t*)alloc((size_t)Bb * T * H * 2);
    bf16_t* VT   = (bf16_t*)alloc((size_t)Bb * H * S * 2);
    bf16_t* ENC  = (bf16_t*)alloc((size_t)BT * NH * 2);
    float*  X1   = (float*)alloc((size_t)BT * D * 4);
    bf16_t* NF   = (bf16_t*)alloc((size_t)BT * D * 2);
    const size_t scBytes = (size_t)16 * T * S * 2;          // 128 MB (bf16, both b)
    const size_t hBytes  = (size_t)BT * F * 2;              // 128 MB
    const size_t headBytes = (scBytes > hBytes) ? scBytes : hBytes;
    char* big = alloc(headBytes + (size_t)2 * BT * D * 4);  // + split-K partials
    bf16_t* SCb   = (bf16_t*)big;                           // scores/probs (in-place)
    bf16_t* Hb    = (bf16_t*)big;                           // aliases SCb (dead by FFN)
    float*  PARTK = (float*)(big + headBytes);              // 64 MB tail
    (void)ws_size; (void)in_sizes; (void)n_in; (void)out_size;

    const dim3 tb(32, 8);
    transpose_f2b<<<dim3(H / 32, D / 32, 8), tb, 0, stream>>>(Wq,  WQT,  D,  H, (long)D * H, (long)H * D);
    transpose_f2b<<<dim3(H / 32, D / 32, 2), tb, 0, stream>>>(Wkv, WKVT, D,  H, (long)D * H, (long)H * D);
    transpose_f2b<<<dim3(D / 32, NH / 32, 1), tb, 0, stream>>>(Wo, WOT, NH,  D, 0, 0);
    transpose_f2b<<<dim3(F / 32, D / 32, 2), tb, 0, stream>>>(Wg,  WGT,  D,  F, (long)D * F, (long)F * D);
    transpose_f2b<<<dim3(D / 32, F / 32, 1), tb, 0, stream>>>(Wl,  WLT,  F,  D, 0, 0);
    modk_part<<<dim3(D3 / 256, Bb, NZ), 256, 0, stream>>>(cond, Wmod_a, PART, D3, KSLICE);
    modk_reduce<<<dim3(D3 / 256, Bb), 256, 0, stream>>>(PART, bmod_a, MODA, D3, NZ);
    modk_part<<<dim3(D3 / 256, Bb, NZ), 256, 0, stream>>>(cond, Wmod_f, PART, D3, KSLICE);
    modk_reduce<<<dim3(D3 / 256, Bb), 256, 0, stream>>>(PART, bmod_f, MODF, D3, NZ);
    rmsnorm_adaln<<<BT, 256, 0, stream>>>(x, MODA, NA, D, T, D3);
    // fused Q+KV projection (N=2560, 256^2 pipelined)
    gemma<EPI_BF16><<<dim3(NQKV / 256, BT / 256, 1), 512, 0, stream>>>(
        NA, WQT, QKVP, D, D, D, NQKV, 0, nullptr, nullptr, 0, 0, nullptr);
    rope_q<<<dim3(T, Nh, Bb), 128, 0, stream>>>(QKVP, pos, Qr, T, NQKV, H);
    rope_kv<<<dim3(T, Bb), 128, 0, stream>>>(QKVP + NH, pos, Kr, VT, T, H, S, NQKV);
    // attention, z-batched over (b,g): z = b*8+g, 16 planes
    // QK^T -> bf16 scores [z][T][S]
    gemm_bt<EPI_BF16, 1><<<dim3(S / 128, T / 128, 16), 256, 0, stream>>>(
        Qr, Kr, SCb, T, S, H, H, H, S,
        (long)T * H, (long)T * H, (long)T * S, 8L * T * S);
    // causal softmax in-place
    softmax_causal<<<dim3(T, 16), 256, 0, stream>>>(SCb, T, S);
    // PV -> ENC[b*T+t][g*H + h]
    gemm_bt<EPI_BF16, 2><<<dim3(H / 128, T / 128, 16), 256, 0, stream>>>(
        SCb, VT, ENC, T, H, S, S, S, NH,
        (long)T * S, (long)H * S, (long)H, (long)T * NH);
    // Wo projection, split-K=2 (full GPU) + combine with gated residual -> X1
    gemma<EPI_F32><<<dim3(D / 256, BT / 256, 2), 512, 0, stream>>>(
        ENC, WOT, PARTK, NH / 2, NH, NH, D, (long)BT * D, nullptr, nullptr, 0, 0, nullptr);
    combine_splitk<<<2048, 256, 0, stream>>>(
        PARTK, x, MODA + 2 * D, X1, D, T, D3, (long)BT * D, (long)BT * D / 4);
    rmsnorm_adaln<<<BT, 256, 0, stream>>>(X1, MODF, NF, D, T, D3);
    // FFN up: h0 = gelu(n@Wg0); h = h0 * (n@Wg1) in-place
    gemma<EPI_GELU><<<dim3(F / 256, BT / 256, 1), 512, 0, stream>>>(
        NF, WGT, Hb, D, D, D, F, 0, nullptr, nullptr, 0, 0, nullptr);
    gemma<EPI_MUL><<<dim3(F / 256, BT / 256, 1), 512, 0, stream>>>(
        NF, WGT + (long)F * D, Hb, D, D, D, F, 0, nullptr, nullptr, 0, 0, Hb);
    // FFN down: split-K=2 partials + fused combine -> out
    gemma<EPI_F32><<<dim3(D / 256, BT / 256, 2), 512, 0, stream>>>(
        Hb, WLT, PARTK, F / 2, F, F, D, (long)BT * D, nullptr, nullptr, 0, 0, nullptr);
    combine_splitk<<<2048, 256, 0, stream>>>(
        PARTK, X1, MODF + 2 * D, (float*)d_out, D, T, D3, (long)BT * D, (long)BT * D / 4);
}